// Round 1
// baseline (905.248 us; speedup 1.0000x reference)
//
#include <hip/hip_runtime.h>
#include <math.h>

#define NN 40000
#define NE 600000
#define NG 64
#define DIM_IN 128
#define HH 128
#define HH2 256

__device__ __forceinline__ int lower_bound_dev(const int* a, int n, int key) {
    int lo = 0, hi = n;
    while (lo < hi) { int mid = (lo + hi) >> 1; if (a[mid] < key) lo = mid + 1; else hi = mid; }
    return lo;
}

// ---------------- CSR build (dst-sorted edge list) ----------------
__global__ void count_kernel(const int* __restrict__ dst, int* __restrict__ counts) {
    int e = blockIdx.x * blockDim.x + threadIdx.x;
    if (e < NE) atomicAdd(&counts[dst[e]], 1);
}

__global__ __launch_bounds__(1024) void scan_kernel(const int* __restrict__ counts,
                                                    int* __restrict__ row_ptr,
                                                    int* __restrict__ cursor) {
    __shared__ int sdata[1024];
    int t = threadIdx.x;
    if (t == 0) row_ptr[0] = 0;
    int carry = 0;
    for (int base = 0; base < NN; base += 1024) {
        int i = base + t;
        int v = (i < NN) ? counts[i] : 0;
        sdata[t] = v;
        __syncthreads();
        for (int off = 1; off < 1024; off <<= 1) {
            int add = (t >= off) ? sdata[t - off] : 0;
            __syncthreads();
            sdata[t] += add;
            __syncthreads();
        }
        int incl = sdata[t] + carry;
        if (i < NN) { row_ptr[i + 1] = incl; cursor[i] = incl - v; }
        carry += sdata[1023];   // chunk total (valid after last sync in scan loop)
        __syncthreads();        // before next chunk overwrites sdata
    }
}

__global__ void fill_kernel(const int* __restrict__ src, const int* __restrict__ dst,
                            const float* __restrict__ eattr, int* __restrict__ cursor,
                            int* __restrict__ src_s, float* __restrict__ attr_s) {
    int e = blockIdx.x * blockDim.x + threadIdx.x;
    if (e < NE) {
        int pos = atomicAdd(&cursor[dst[e]], 1);
        src_s[pos] = src[e];
        attr_s[pos] = eattr[e];
    }
}

// ------------- scatter-softmax aggregation, online, one block per node -------------
__global__ __launch_bounds__(128) void agg_kernel(
    const float* __restrict__ xn,
    const int* __restrict__ row_ptr,
    const int* __restrict__ src_s, const float* __restrict__ attr_s,
    const float* __restrict__ ew, const float* __restrict__ eb,
    const float* __restrict__ tptr, int layer,
    float* __restrict__ out)
{
    int d = blockIdx.x;
    int c = threadIdx.x;                    // channel 0..127
    int beg = row_ptr[d], end = row_ptr[d + 1];
    float tc = tptr[layer];
    float ewc = ew[c], ebc = eb[c];
    float m = -INFINITY, den = 0.f, num = 0.f;
    for (int p = beg; p < end; ++p) {
        int s = src_s[p];
        float a = attr_s[p];
        float msg = fmaxf(__fmaf_rn(a, ewc, ebc) + xn[(size_t)s * HH + c], 0.f) + 1e-7f;
        float logit = msg * tc;
        float nm = fmaxf(m, logit);
        float sc = __expf(m - nm);          // first iter: exp(-inf)=0
        float ex = __expf(logit - nm);
        den = den * sc + ex;
        num = num * sc + ex * msg;
        m = nm;
    }
    float agg = num / fmaxf(den, 1e-16f);   // deg==0 -> 0
    out[(size_t)d * HH + c] = agg + xn[(size_t)d * HH + c];
}

// ------------- fp32 tiled GEMM: C[M,N] = A[M,K]@B[K,N] + bias (+C) (+relu) -------------
// BM=BN=64, BK=16, 64 threads (1 wave), 8x8 per thread.
template<int RELU, int ADD_RES>
__global__ __launch_bounds__(64) void gemm64(
    const float* __restrict__ A, const float* __restrict__ B,
    const float* __restrict__ bias, float* __restrict__ C,
    int M, int N, int K)
{
    __shared__ float As[16][68];   // [k][m], pad 4 keeps float4 alignment
    __shared__ float Bs[16][68];   // [k][n]
    int t = threadIdx.x;
    int tx = t & 7;                 // n-dir (x8)
    int ty = t >> 3;                // m-dir (x8)
    int row0 = blockIdx.y * 64, col0 = blockIdx.x * 64;
    float acc[8][8] = {};
    for (int k0 = 0; k0 < K; k0 += 16) {
        const float* Arow = A + (size_t)(row0 + t) * K + k0;
        #pragma unroll
        for (int j = 0; j < 4; ++j) {
            float4 a4 = *(const float4*)(Arow + 4 * j);
            As[4*j+0][t] = a4.x; As[4*j+1][t] = a4.y;
            As[4*j+2][t] = a4.z; As[4*j+3][t] = a4.w;
        }
        {
            int kb = t >> 2, nb = (t & 3) * 16;
            const float* Brow = B + (size_t)(k0 + kb) * N + col0 + nb;
            #pragma unroll
            for (int cidx = 0; cidx < 4; ++cidx)
                *(float4*)&Bs[kb][nb + 4*cidx] = *(const float4*)(Brow + 4*cidx);
        }
        __syncthreads();
        #pragma unroll
        for (int kk = 0; kk < 16; ++kk) {
            float av[8], bv[8];
            *(float4*)&av[0] = *(const float4*)&As[kk][ty*8];
            *(float4*)&av[4] = *(const float4*)&As[kk][ty*8+4];
            *(float4*)&bv[0] = *(const float4*)&Bs[kk][tx*8];
            *(float4*)&bv[4] = *(const float4*)&Bs[kk][tx*8+4];
            #pragma unroll
            for (int i = 0; i < 8; ++i)
                #pragma unroll
                for (int j = 0; j < 8; ++j)
                    acc[i][j] = __fmaf_rn(av[i], bv[j], acc[i][j]);
        }
        __syncthreads();
    }
    #pragma unroll
    for (int i = 0; i < 8; ++i) {
        int r = row0 + ty*8 + i;
        float* Crow = C + (size_t)r * N + col0 + tx*8;
        #pragma unroll
        for (int j = 0; j < 8; j += 4) {
            float4 v;
            float* vv = (float*)&v;
            #pragma unroll
            for (int q = 0; q < 4; ++q) {
                float xv = acc[i][j+q] + bias[col0 + tx*8 + j + q];
                if (ADD_RES) xv += Crow[j+q];
                if (RELU) xv = fmaxf(xv, 0.f);
                vv[q] = xv;
            }
            *(float4*)(Crow + j) = v;
        }
    }
}

// ------------- row-wise LayerNorm + ReLU, one wave per row -------------
template<int W>
__global__ __launch_bounds__(256) void ln_relu_kernel(
    const float* __restrict__ X, const float* __restrict__ g,
    const float* __restrict__ b, float* __restrict__ Y, int M)
{
    int wid = (blockIdx.x * blockDim.x + threadIdx.x) >> 6;
    int lane = threadIdx.x & 63;
    if (wid >= M) return;
    const float* x = X + (size_t)wid * W;
    constexpr int C = W / 64;
    float v[C]; float s = 0.f, s2 = 0.f;
    #pragma unroll
    for (int i = 0; i < C; ++i) { v[i] = x[lane + 64*i]; s += v[i]; s2 += v[i]*v[i]; }
    #pragma unroll
    for (int off = 32; off > 0; off >>= 1) {
        s  += __shfl_down(s,  off, 64);
        s2 += __shfl_down(s2, off, 64);
    }
    s = __shfl(s, 0, 64); s2 = __shfl(s2, 0, 64);
    float mu = s * (1.0f / W);
    float var = s2 * (1.0f / W) - mu * mu;   // matches jnp.var
    float rstd = rsqrtf(var + 1e-5f);
    float* y = Y + (size_t)wid * W;
    #pragma unroll
    for (int i = 0; i < C; ++i) {
        int cc = lane + 64*i;
        float o = (v[i] - mu) * rstd * g[cc] + b[cc];
        y[cc] = fmaxf(o, 0.f);
    }
}

// ------------- mean pool over sorted batch (partial sums + atomics) -------------
__global__ __launch_bounds__(128) void pool_kernel(
    const float* __restrict__ f, const int* __restrict__ batch, float* __restrict__ pooled)
{
    int g = blockIdx.x;
    int chunk = blockIdx.y;
    int c = threadIdx.x;
    int s = lower_bound_dev(batch, NN, g);
    int e = lower_bound_dev(batch, NN, g + 1);
    int len = e - s;
    if (len <= 0) return;
    int nch = gridDim.y;
    int per = (len + nch - 1) / nch;
    int cs = s + chunk * per;
    int ce = min(cs + per, e);
    if (cs >= ce) return;
    float acc = 0.f;
    for (int n = cs; n < ce; ++n) acc += f[(size_t)n*HH + c];
    atomicAdd(&pooled[g*HH + c], acc);
}

// ------------- MLP head: (pooled/cnt)@hw1->relu->@hw2->relu->@hw3 -------------
__global__ __launch_bounds__(128) void head_kernel(
    const float* __restrict__ pooled, const int* __restrict__ batch,
    const float* __restrict__ hw1, const float* __restrict__ hb1,
    const float* __restrict__ hw2, const float* __restrict__ hb2,
    const float* __restrict__ hw3, const float* __restrict__ hb3,
    float* __restrict__ out)
{
    __shared__ float p[HH];
    __shared__ float o1[64];
    __shared__ float o2[32];
    int g = blockIdx.x;
    int t = threadIdx.x;
    int s = lower_bound_dev(batch, NN, g);
    int e = lower_bound_dev(batch, NN, g + 1);
    float cnt = fmaxf((float)(e - s), 1.0f);
    p[t] = pooled[g*HH + t] / cnt;
    __syncthreads();
    if (t < 64) {
        float acc = hb1[t];
        for (int k = 0; k < HH; ++k) acc += p[k] * hw1[k*64 + t];
        o1[t] = fmaxf(acc, 0.f);
    }
    __syncthreads();
    if (t < 32) {
        float acc = hb2[t];
        for (int k = 0; k < 64; ++k) acc += o1[k] * hw2[k*32 + t];
        o2[t] = fmaxf(acc, 0.f);
    }
    __syncthreads();
    if (t == 0) {
        float acc = hb3[0];
        for (int k = 0; k < 32; ++k) acc += o2[k] * hw3[k];
        out[g] = acc;
    }
}

extern "C" void kernel_launch(void* const* d_in, const int* in_sizes, int n_in,
                              void* d_out, int out_size, void* d_ws, size_t ws_size,
                              hipStream_t stream)
{
    const float* x      = (const float*)d_in[0];
    const float* eattr  = (const float*)d_in[1];
    const float* node_w = (const float*)d_in[2];
    const float* node_b = (const float*)d_in[3];
    const float* edge_w = (const float*)d_in[4];
    const float* edge_b = (const float*)d_in[5];
    const float* tptr   = (const float*)d_in[6];
    const float* lin1_w = (const float*)d_in[7];
    const float* lin1_b = (const float*)d_in[8];
    const float* ln1_g  = (const float*)d_in[9];
    const float* ln1_bt = (const float*)d_in[10];
    const float* lin2_w = (const float*)d_in[11];
    const float* lin2_b = (const float*)d_in[12];
    const float* blk_g  = (const float*)d_in[13];
    const float* blk_b  = (const float*)d_in[14];
    const float* hw1    = (const float*)d_in[15];
    const float* hb1    = (const float*)d_in[16];
    const float* hw2    = (const float*)d_in[17];
    const float* hb2    = (const float*)d_in[18];
    const float* hw3    = (const float*)d_in[19];
    const float* hb3    = (const float*)d_in[20];
    const int*   eidx   = (const int*)d_in[21];
    const int*   batch  = (const int*)d_in[22];
    const int* src = eidx;
    const int* dst = eidx + NE;
    float* out = (float*)d_out;

    // ---- workspace carve (~107 MB total) ----
    char* ws = (char*)d_ws;
    size_t off = 0;
    auto carve = [&](size_t bytes) -> char* {
        char* p = ws + off;
        off = (off + bytes + 255) & ~(size_t)255;
        return p;
    };
    float* h      = (float*)carve((size_t)NN*HH*4);
    float* r      = (float*)carve((size_t)NN*HH*4);
    float* o      = (float*)carve((size_t)NN*HH*4);
    float* t2     = (float*)carve((size_t)NN*HH2*4);
    int*   counts = (int*)carve((size_t)NN*4);
    int*   rowp   = (int*)carve((size_t)(NN+1)*4);
    int*   cursor = (int*)carve((size_t)NN*4);
    int*   src_s  = (int*)carve((size_t)NE*4);
    float* attr_s = (float*)carve((size_t)NE*4);
    float* pooled = (float*)carve((size_t)NG*HH*4);

    hipMemsetAsync(counts, 0, (size_t)NN*4, stream);
    hipMemsetAsync(pooled, 0, (size_t)NG*HH*4, stream);
    count_kernel<<<(NE+255)/256, 256, 0, stream>>>(dst, counts);
    scan_kernel<<<1, 1024, 0, stream>>>(counts, rowp, cursor);
    fill_kernel<<<(NE+255)/256, 256, 0, stream>>>(src, dst, eattr, cursor, src_s, attr_s);

    // node linear: h = x @ node_w + node_b
    gemm64<0,0><<<dim3(HH/64, NN/64), 64, 0, stream>>>(x, node_w, node_b, h, NN, HH, DIM_IN);

    for (int layer = 0; layer < 3; ++layer) {
        const float* xn;
        if (layer == 0) xn = h;
        else {
            ln_relu_kernel<HH><<<(NN+3)/4, 256, 0, stream>>>(h, blk_g + layer*HH, blk_b + layer*HH, r, NN);
            xn = r;
        }
        agg_kernel<<<NN, 128, 0, stream>>>(xn, rowp, src_s, attr_s, edge_w, edge_b, tptr, layer, o);
        gemm64<0,0><<<dim3(HH2/64, NN/64), 64, 0, stream>>>(
            o, lin1_w + (size_t)layer*HH*HH2, lin1_b + (size_t)layer*HH2, t2, NN, HH2, HH);
        ln_relu_kernel<HH2><<<(NN+3)/4, 256, 0, stream>>>(
            t2, ln1_g + (size_t)layer*HH2, ln1_bt + (size_t)layer*HH2, t2, NN);
        if (layer == 0)
            gemm64<0,0><<<dim3(HH/64, NN/64), 64, 0, stream>>>(
                t2, lin2_w + (size_t)layer*HH2*HH, lin2_b + (size_t)layer*HH, h, NN, HH, HH2);
        else
            gemm64<0,1><<<dim3(HH/64, NN/64), 64, 0, stream>>>(
                t2, lin2_w + (size_t)layer*HH2*HH, lin2_b + (size_t)layer*HH, h, NN, HH, HH2);
    }

    // final norm+act (layer-0 block params), pool, head
    ln_relu_kernel<HH><<<(NN+3)/4, 256, 0, stream>>>(h, blk_g, blk_b, r, NN);
    pool_kernel<<<dim3(NG, 8), 128, 0, stream>>>(r, batch, pooled);
    head_kernel<<<NG, 128, 0, stream>>>(pooled, batch, hw1, hb1, hw2, hb2, hw3, hb3, out);
}

// Round 2
// 620.374 us; speedup vs baseline: 1.4592x; 1.4592x over previous
//
#include <hip/hip_runtime.h>
#include <math.h>

#define NN 40000
#define NE 600000
#define NG 64
#define DIM_IN 128
#define HH 128
#define HH2 256

using half8 = __attribute__((ext_vector_type(8))) _Float16;
using h2    = __attribute__((ext_vector_type(2))) _Float16;
using f4    = __attribute__((ext_vector_type(4))) float;

__device__ __forceinline__ int lower_bound_dev(const int* a, int n, int key) {
    int lo = 0, hi = n;
    while (lo < hi) { int mid = (lo + hi) >> 1; if (a[mid] < key) lo = mid + 1; else hi = mid; }
    return lo;
}

// ---------------- weight/input fp32 -> fp16 conversion (+ B^T layouts) ----------------
// ranges: [0, NX): xh = half(x)
//         [NX, NX+16384): nwt[n*128+k] = node_w[k*128+n]
//         next 98304: w1t[l][n*128+k] = lin1_w[l][k*256+n]   (n<256,k<128)
//         next 98304: w2t[l][n*256+k] = lin2_w[l][k*128+n]   (n<128,k<256)
#define NX (NN*DIM_IN)
__global__ void convert_kernel(const float* __restrict__ x, const float* __restrict__ node_w,
                               const float* __restrict__ lin1_w, const float* __restrict__ lin2_w,
                               _Float16* __restrict__ xh, _Float16* __restrict__ nwt,
                               _Float16* __restrict__ w1t, _Float16* __restrict__ w2t)
{
    int id = blockIdx.x * blockDim.x + threadIdx.x;
    if (id < NX) { xh[id] = (_Float16)x[id]; return; }
    id -= NX;
    if (id < 16384) { int n = id >> 7, k = id & 127; nwt[id] = (_Float16)node_w[k*128 + n]; return; }
    id -= 16384;
    if (id < 98304) {
        int l = id >> 15, r = id & 32767;
        int n = r >> 7, k = r & 127;
        w1t[id] = (_Float16)lin1_w[l*32768 + k*256 + n];
        return;
    }
    id -= 98304;
    if (id < 98304) {
        int l = id >> 15, r = id & 32767;
        int n = r >> 8, k = r & 255;
        w2t[id] = (_Float16)lin2_w[l*32768 + k*128 + n];
    }
}

// ---------------- CSR build (dst-sorted edge list) ----------------
__global__ void count_kernel(const int* __restrict__ dst, int* __restrict__ counts) {
    int e = blockIdx.x * blockDim.x + threadIdx.x;
    if (e < NE) atomicAdd(&counts[dst[e]], 1);
}

__global__ __launch_bounds__(1024) void scan_kernel(const int* __restrict__ counts,
                                                    int* __restrict__ row_ptr,
                                                    int* __restrict__ cursor) {
    __shared__ int wpre[16];
    __shared__ int tot;
    int t = threadIdx.x, lane = t & 63, wid = t >> 6;
    if (t == 0) row_ptr[0] = 0;
    int carry = 0;
    for (int base = 0; base < NN; base += 1024) {
        int i = base + t;
        int v = (i < NN) ? counts[i] : 0;
        int s = v;
        #pragma unroll
        for (int off = 1; off < 64; off <<= 1) {
            int u = __shfl_up(s, off, 64);
            if (lane >= off) s += u;
        }
        if (lane == 63) wpre[wid] = s;
        __syncthreads();
        if (t == 0) {
            int run = 0;
            #pragma unroll
            for (int j = 0; j < 16; ++j) { int xv = wpre[j]; wpre[j] = run; run += xv; }
            tot = run;
        }
        __syncthreads();
        int incl = s + wpre[wid] + carry;
        if (i < NN) { row_ptr[i + 1] = incl; cursor[i] = incl - v; }
        carry += tot;
        __syncthreads();
    }
}

__global__ void fill_kernel(const int* __restrict__ src, const int* __restrict__ dst,
                            const float* __restrict__ eattr, int* __restrict__ cursor,
                            int* __restrict__ src_s, float* __restrict__ attr_s) {
    int e = blockIdx.x * blockDim.x + threadIdx.x;
    if (e < NE) {
        int pos = atomicAdd(&cursor[dst[e]], 1);
        src_s[pos] = src[e];
        attr_s[pos] = eattr[e];
    }
}

// ------------- scatter-softmax aggregation, no-max (values bounded), fp16 gather -------------
// 4 nodes per 256-thread block; 64 lanes per node, 2 channels per lane via half2.
__global__ __launch_bounds__(256) void agg_kernel(
    const _Float16* __restrict__ xh,
    const int* __restrict__ row_ptr,
    const int* __restrict__ src_s, const float* __restrict__ attr_s,
    const float* __restrict__ ew, const float* __restrict__ eb,
    const float* __restrict__ tptr, int layer,
    _Float16* __restrict__ oh)
{
    int d = blockIdx.x * 4 + (threadIdx.x >> 6);
    int lane = threadIdx.x & 63;
    int c0 = 2 * lane, c1 = c0 + 1;
    float tc = tptr[layer];
    float ew0 = ew[c0], eb0 = eb[c0];
    float ew1 = ew[c1], eb1 = eb[c1];
    int beg = row_ptr[d], end = row_ptr[d + 1];
    float den0 = 0.f, num0 = 0.f, den1 = 0.f, num1 = 0.f;
    for (int p = beg; p < end; ++p) {
        int s = src_s[p];
        float a = attr_s[p];
        h2 hv = *(const h2*)(xh + ((size_t)s << 7) + c0);
        float m0 = fmaxf(__fmaf_rn(a, ew0, eb0) + (float)hv.x, 0.f) + 1e-7f;
        float m1 = fmaxf(__fmaf_rn(a, ew1, eb1) + (float)hv.y, 0.f) + 1e-7f;
        float e0 = __expf(m0 * tc);
        float e1 = __expf(m1 * tc);
        den0 += e0; num0 = __fmaf_rn(e0, m0, num0);
        den1 += e1; num1 = __fmaf_rn(e1, m1, num1);
    }
    h2 sv = *(const h2*)(xh + ((size_t)d << 7) + c0);
    float o0 = num0 / fmaxf(den0, 1e-16f) + (float)sv.x;
    float o1 = num1 / fmaxf(den1, 1e-16f) + (float)sv.y;
    h2 ov; ov.x = (_Float16)o0; ov.y = (_Float16)o1;
    *(h2*)(oh + ((size_t)d << 7) + c0) = ov;
}

// ------------- fp16 MFMA GEMM: C[M,N] = A[M,K] @ Bt[N,K]^T + bias -------------
// 256 threads = 4 waves (2x2), block tile 64x128, BK=32, wave tile 32x64 (2x4 of 16x16x32).
// EPI: 0 = write half, 1 = write float, 2 = float in-place += (residual)
template<int EPI>
__global__ __launch_bounds__(256) void gemm_mfma(
    const _Float16* __restrict__ A, const _Float16* __restrict__ Bt,
    const float* __restrict__ bias, void* __restrict__ Cv,
    int M, int N, int K)
{
    constexpr int LDA = 40;                 // halves; 80B row stride (bank-spread)
    __shared__ _Float16 As[64 * LDA];
    __shared__ _Float16 Bs[128 * LDA];
    int t = threadIdx.x;
    int row0 = blockIdx.y * 64;
    int col0 = blockIdx.x * 128;
    int w = t >> 6, lane = t & 63;
    int wm = w & 1, wn = w >> 1;            // 2 waves in M, 2 in N
    int q = lane >> 4, l16 = lane & 15;
    f4 acc[2][4];
    #pragma unroll
    for (int i = 0; i < 2; ++i)
        #pragma unroll
        for (int j = 0; j < 4; ++j)
            acc[i][j] = (f4){0.f, 0.f, 0.f, 0.f};

    for (int k0 = 0; k0 < K; k0 += 32) {
        {   // stage A: 64 rows x 32 halves, 16B per thread
            int r = t >> 2, seg = t & 3;
            *(float4*)&As[r * LDA + seg * 8] =
                *(const float4*)(A + (size_t)(row0 + r) * K + k0 + seg * 8);
        }
        #pragma unroll
        for (int i = 0; i < 2; ++i) {       // stage Bt: 128 rows x 32 halves
            int idx = t + i * 256;
            int r = idx >> 2, seg = idx & 3;
            *(float4*)&Bs[r * LDA + seg * 8] =
                *(const float4*)(Bt + (size_t)(col0 + r) * K + k0 + seg * 8);
        }
        __syncthreads();
        half8 af[2], bf[4];
        #pragma unroll
        for (int i = 0; i < 2; ++i)
            af[i] = *(const half8*)&As[(wm * 32 + i * 16 + l16) * LDA + q * 8];
        #pragma unroll
        for (int j = 0; j < 4; ++j)
            bf[j] = *(const half8*)&Bs[(wn * 64 + j * 16 + l16) * LDA + q * 8];
        #pragma unroll
        for (int i = 0; i < 2; ++i)
            #pragma unroll
            for (int j = 0; j < 4; ++j)
                acc[i][j] = __builtin_amdgcn_mfma_f32_16x16x32_f16(af[i], bf[j], acc[i][j], 0, 0, 0);
        __syncthreads();
    }
    // epilogue: C/D frag mapping col=lane&15, row=quad*4+reg
    #pragma unroll
    for (int j = 0; j < 4; ++j) {
        int col = col0 + wn * 64 + j * 16 + l16;
        float bv = bias[col];
        #pragma unroll
        for (int i = 0; i < 2; ++i) {
            int rbase = row0 + wm * 32 + i * 16 + q * 4;
            #pragma unroll
            for (int rg = 0; rg < 4; ++rg) {
                float val = acc[i][j][rg] + bv;
                size_t idx = (size_t)(rbase + rg) * N + col;
                if (EPI == 0)      ((_Float16*)Cv)[idx] = (_Float16)val;
                else if (EPI == 1) ((float*)Cv)[idx] = val;
                else               ((float*)Cv)[idx] += val;
            }
        }
    }
}

// ------------- row-wise LayerNorm + ReLU, one wave per row -------------
template<int W, int HALF_OUT>
__global__ __launch_bounds__(256) void ln_relu_kernel(
    const float* __restrict__ X, const float* __restrict__ g,
    const float* __restrict__ b, void* __restrict__ Yv, int M)
{
    int wid = (blockIdx.x * blockDim.x + threadIdx.x) >> 6;
    int lane = threadIdx.x & 63;
    if (wid >= M) return;
    const float* x = X + (size_t)wid * W;
    constexpr int C = W / 64;
    float v[C]; float s = 0.f, s2 = 0.f;
    #pragma unroll
    for (int i = 0; i < C; ++i) { v[i] = x[lane + 64 * i]; s += v[i]; s2 += v[i] * v[i]; }
    #pragma unroll
    for (int off = 32; off > 0; off >>= 1) {
        s  += __shfl_down(s,  off, 64);
        s2 += __shfl_down(s2, off, 64);
    }
    s = __shfl(s, 0, 64); s2 = __shfl(s2, 0, 64);
    float mu = s * (1.0f / W);
    float var = s2 * (1.0f / W) - mu * mu;
    float rstd = rsqrtf(var + 1e-5f);
    #pragma unroll
    for (int i = 0; i < C; ++i) {
        int cc = lane + 64 * i;
        float o = fmaxf((v[i] - mu) * rstd * g[cc] + b[cc], 0.f);
        if (HALF_OUT) ((_Float16*)Yv)[(size_t)wid * W + cc] = (_Float16)o;
        else          ((float*)Yv)[(size_t)wid * W + cc] = o;
    }
}

// ------------- mean pool over sorted batch (partial sums + atomics) -------------
__global__ __launch_bounds__(128) void pool_kernel(
    const float* __restrict__ f, const int* __restrict__ batch, float* __restrict__ pooled)
{
    int g = blockIdx.x;
    int chunk = blockIdx.y;
    int c = threadIdx.x;
    int s = lower_bound_dev(batch, NN, g);
    int e = lower_bound_dev(batch, NN, g + 1);
    int len = e - s;
    if (len <= 0) return;
    int nch = gridDim.y;
    int per = (len + nch - 1) / nch;
    int cs = s + chunk * per;
    int ce = min(cs + per, e);
    if (cs >= ce) return;
    float acc = 0.f;
    for (int n = cs; n < ce; ++n) acc += f[(size_t)n * HH + c];
    atomicAdd(&pooled[g * HH + c], acc);
}

// ------------- MLP head -------------
__global__ __launch_bounds__(128) void head_kernel(
    const float* __restrict__ pooled, const int* __restrict__ batch,
    const float* __restrict__ hw1, const float* __restrict__ hb1,
    const float* __restrict__ hw2, const float* __restrict__ hb2,
    const float* __restrict__ hw3, const float* __restrict__ hb3,
    float* __restrict__ out)
{
    __shared__ float p[HH];
    __shared__ float o1[64];
    __shared__ float o2[32];
    int g = blockIdx.x;
    int t = threadIdx.x;
    int s = lower_bound_dev(batch, NN, g);
    int e = lower_bound_dev(batch, NN, g + 1);
    float cnt = fmaxf((float)(e - s), 1.0f);
    p[t] = pooled[g * HH + t] / cnt;
    __syncthreads();
    if (t < 64) {
        float acc = hb1[t];
        for (int k = 0; k < HH; ++k) acc += p[k] * hw1[k * 64 + t];
        o1[t] = fmaxf(acc, 0.f);
    }
    __syncthreads();
    if (t < 32) {
        float acc = hb2[t];
        for (int k = 0; k < 64; ++k) acc += o1[k] * hw2[k * 32 + t];
        o2[t] = fmaxf(acc, 0.f);
    }
    __syncthreads();
    if (t == 0) {
        float acc = hb3[0];
        for (int k = 0; k < 32; ++k) acc += o2[k] * hw3[k];
        out[g] = acc;
    }
}

extern "C" void kernel_launch(void* const* d_in, const int* in_sizes, int n_in,
                              void* d_out, int out_size, void* d_ws, size_t ws_size,
                              hipStream_t stream)
{
    const float* x      = (const float*)d_in[0];
    const float* eattr  = (const float*)d_in[1];
    const float* node_w = (const float*)d_in[2];
    const float* node_b = (const float*)d_in[3];
    const float* edge_w = (const float*)d_in[4];
    const float* edge_b = (const float*)d_in[5];
    const float* tptr   = (const float*)d_in[6];
    const float* lin1_w = (const float*)d_in[7];
    const float* lin1_b = (const float*)d_in[8];
    const float* ln1_g  = (const float*)d_in[9];
    const float* ln1_bt = (const float*)d_in[10];
    const float* lin2_w = (const float*)d_in[11];
    const float* lin2_b = (const float*)d_in[12];
    const float* blk_g  = (const float*)d_in[13];
    const float* blk_b  = (const float*)d_in[14];
    const float* hw1    = (const float*)d_in[15];
    const float* hb1    = (const float*)d_in[16];
    const float* hw2    = (const float*)d_in[17];
    const float* hb2    = (const float*)d_in[18];
    const float* hw3    = (const float*)d_in[19];
    const float* hb3    = (const float*)d_in[20];
    const int*   eidx   = (const int*)d_in[21];
    const int*   batch  = (const int*)d_in[22];
    const int* src = eidx;
    const int* dst = eidx + NE;
    float* out = (float*)d_out;

    // ---- workspace carve (~108 MB) ----
    char* ws = (char*)d_ws;
    size_t off = 0;
    auto carve = [&](size_t bytes) -> char* {
        char* p = ws + off;
        off = (off + bytes + 255) & ~(size_t)255;
        return p;
    };
    float*    h      = (float*)carve((size_t)NN * HH * 4);
    float*    t2     = (float*)carve((size_t)NN * HH2 * 4);   // also hosts xh_in / r overlays
    _Float16* xnh    = (_Float16*)carve((size_t)NN * HH * 2); // agg input (half)
    _Float16* oh     = (_Float16*)carve((size_t)NN * HH * 2); // agg output (half)
    _Float16* t2h    = (_Float16*)carve((size_t)NN * HH2 * 2);
    _Float16* nwt    = (_Float16*)carve((size_t)16384 * 2);
    _Float16* w1t    = (_Float16*)carve((size_t)98304 * 2);
    _Float16* w2t    = (_Float16*)carve((size_t)98304 * 2);
    int*      counts = (int*)carve((size_t)NN * 4);
    int*      rowp   = (int*)carve((size_t)(NN + 1) * 4);
    int*      cursor = (int*)carve((size_t)NN * 4);
    int*      src_s  = (int*)carve((size_t)NE * 4);
    float*    attr_s = (float*)carve((size_t)NE * 4);
    float*    pooled = (float*)carve((size_t)NG * HH * 4);
    _Float16* xh_in  = (_Float16*)t2;   // dead once lin1 (layer 0) writes t2
    float*    r      = t2;              // final-LN out; t2 dead by then

    hipMemsetAsync(counts, 0, (size_t)NN * 4, stream);
    hipMemsetAsync(pooled, 0, (size_t)NG * HH * 4, stream);

    {   // conversions: x->half, weights -> half B^T layouts
        int total = NX + 16384 + 98304 + 98304;
        convert_kernel<<<(total + 255) / 256, 256, 0, stream>>>(
            x, node_w, lin1_w, lin2_w, xh_in, nwt, w1t, w2t);
    }
    count_kernel<<<(NE + 255) / 256, 256, 0, stream>>>(dst, counts);
    scan_kernel<<<1, 1024, 0, stream>>>(counts, rowp, cursor);
    fill_kernel<<<(NE + 255) / 256, 256, 0, stream>>>(src, dst, eattr, cursor, src_s, attr_s);

    // node linear: xnh = half(x @ node_w + node_b)
    gemm_mfma<0><<<dim3(HH / 128, NN / 64), 256, 0, stream>>>(
        xh_in, nwt, node_b, xnh, NN, HH, DIM_IN);

    for (int layer = 0; layer < 3; ++layer) {
        if (layer > 0) {   // xnh = half(relu(LN(h)))
            ln_relu_kernel<HH, 1><<<(NN + 3) / 4, 256, 0, stream>>>(
                h, blk_g + layer * HH, blk_b + layer * HH, xnh, NN);
        }
        agg_kernel<<<NN / 4, 256, 0, stream>>>(
            xnh, rowp, src_s, attr_s, edge_w, edge_b, tptr, layer, oh);
        gemm_mfma<1><<<dim3(HH2 / 128, NN / 64), 256, 0, stream>>>(
            oh, w1t + (size_t)layer * 32768, lin1_b + (size_t)layer * HH2, t2, NN, HH2, HH);
        ln_relu_kernel<HH2, 1><<<(NN + 3) / 4, 256, 0, stream>>>(
            t2, ln1_g + (size_t)layer * HH2, ln1_bt + (size_t)layer * HH2, t2h, NN);
        if (layer == 0)
            gemm_mfma<1><<<dim3(HH / 128, NN / 64), 256, 0, stream>>>(
                t2h, w2t + (size_t)layer * 32768, lin2_b + (size_t)layer * HH, h, NN, HH, HH2);
        else
            gemm_mfma<2><<<dim3(HH / 128, NN / 64), 256, 0, stream>>>(
                t2h, w2t + (size_t)layer * 32768, lin2_b + (size_t)layer * HH, h, NN, HH, HH2);
    }

    // final norm+act (layer-0 block params), pool, head
    ln_relu_kernel<HH, 0><<<(NN + 3) / 4, 256, 0, stream>>>(h, blk_g, blk_b, r, NN);
    pool_kernel<<<dim3(NG, 8), 128, 0, stream>>>(r, batch, pooled);
    head_kernel<<<NG, 128, 0, stream>>>(pooled, batch, hw1, hb1, hw2, hb2, hw3, hb3, out);
}

// Round 3
// 457.324 us; speedup vs baseline: 1.9794x; 1.3565x over previous
//
#include <hip/hip_runtime.h>
#include <math.h>

#define NN 40000
#define NE 600000
#define NG 64
#define DIM_IN 128
#define HH 128
#define HH2 256

using half8 = __attribute__((ext_vector_type(8))) _Float16;
using h2    = __attribute__((ext_vector_type(2))) _Float16;
using f4    = __attribute__((ext_vector_type(4))) float;

__device__ __forceinline__ int lower_bound_dev(const int* a, int n, int key) {
    int lo = 0, hi = n;
    while (lo < hi) { int mid = (lo + hi) >> 1; if (a[mid] < key) lo = mid + 1; else hi = mid; }
    return lo;
}

// ---------------- weight/input fp32 -> fp16 conversion (+ B^T layouts) ----------------
#define NX (NN*DIM_IN)
__global__ void convert_kernel(const float* __restrict__ x, const float* __restrict__ node_w,
                               const float* __restrict__ lin1_w, const float* __restrict__ lin2_w,
                               _Float16* __restrict__ xh, _Float16* __restrict__ nwt,
                               _Float16* __restrict__ w1t, _Float16* __restrict__ w2t)
{
    int id = blockIdx.x * blockDim.x + threadIdx.x;
    if (id < NX) { xh[id] = (_Float16)x[id]; return; }
    id -= NX;
    if (id < 16384) { int n = id >> 7, k = id & 127; nwt[id] = (_Float16)node_w[k*128 + n]; return; }
    id -= 16384;
    if (id < 98304) {
        int l = id >> 15, r = id & 32767;
        int n = r >> 7, k = r & 127;
        w1t[id] = (_Float16)lin1_w[l*32768 + k*256 + n];
        return;
    }
    id -= 98304;
    if (id < 98304) {
        int l = id >> 15, r = id & 32767;
        int n = r >> 8, k = r & 255;
        w2t[id] = (_Float16)lin2_w[l*32768 + k*128 + n];
    }
}

// ---------------- CSR build (dst-sorted edge list) ----------------
__global__ void count_kernel(const int* __restrict__ dst, int* __restrict__ counts) {
    int e = blockIdx.x * blockDim.x + threadIdx.x;
    if (e < NE) atomicAdd(&counts[dst[e]], 1);
}

__global__ __launch_bounds__(1024) void scan_kernel(const int* __restrict__ counts,
                                                    int* __restrict__ row_ptr,
                                                    int* __restrict__ cursor) {
    __shared__ int wpre[16];
    __shared__ int tot;
    int t = threadIdx.x, lane = t & 63, wid = t >> 6;
    if (t == 0) row_ptr[0] = 0;
    int carry = 0;
    for (int base = 0; base < NN; base += 1024) {
        int i = base + t;
        int v = (i < NN) ? counts[i] : 0;
        int s = v;
        #pragma unroll
        for (int off = 1; off < 64; off <<= 1) {
            int u = __shfl_up(s, off, 64);
            if (lane >= off) s += u;
        }
        if (lane == 63) wpre[wid] = s;
        __syncthreads();
        if (t == 0) {
            int run = 0;
            #pragma unroll
            for (int j = 0; j < 16; ++j) { int xv = wpre[j]; wpre[j] = run; run += xv; }
            tot = run;
        }
        __syncthreads();
        int incl = s + wpre[wid] + carry;
        if (i < NN) { row_ptr[i + 1] = incl; cursor[i] = incl - v; }
        carry += tot;
        __syncthreads();
    }
}

__global__ void fill_kernel(const int* __restrict__ src, const int* __restrict__ dst,
                            const float* __restrict__ eattr, int* __restrict__ cursor,
                            int* __restrict__ src_s, float* __restrict__ attr_s) {
    int e = blockIdx.x * blockDim.x + threadIdx.x;
    if (e < NE) {
        int pos = atomicAdd(&cursor[dst[e]], 1);
        src_s[pos] = src[e];
        attr_s[pos] = eattr[e];
    }
}

// ------------- scatter-softmax aggregation: batched edge loads + prefetch-8 gathers -------------
__global__ __launch_bounds__(256) void agg_kernel(
    const _Float16* __restrict__ xh,
    const int* __restrict__ row_ptr,
    const int* __restrict__ src_s, const float* __restrict__ attr_s,
    const float* __restrict__ ew, const float* __restrict__ eb,
    const float* __restrict__ tptr, int layer,
    _Float16* __restrict__ oh)
{
    int d = blockIdx.x * 4 + (threadIdx.x >> 6);
    int lane = threadIdx.x & 63;
    int c0 = 2 * lane;
    float tc = tptr[layer];
    float ew0 = ew[c0], eb0 = eb[c0];
    float ew1 = ew[c0 + 1], eb1 = eb[c0 + 1];
    int beg = row_ptr[d], end = row_ptr[d + 1];
    float den0 = 0.f, num0 = 0.f, den1 = 0.f, num1 = 0.f;
    for (int base = beg; base < end; base += 64) {
        int cnt = min(64, end - base);
        int gl = base + min(lane, cnt - 1);
        int sv = src_s[gl];          // one coalesced load covers up to 64 edges
        float av = attr_s[gl];
        for (int j0 = 0; j0 < cnt; j0 += 8) {
            h2 g[8]; float aa[8];
            #pragma unroll
            for (int u = 0; u < 8; ++u) {   // issue 8 gathers before consuming
                int jj = min(j0 + u, cnt - 1);
                int s = __shfl(sv, jj, 64);
                aa[u] = __shfl(av, jj, 64);
                g[u] = *(const h2*)(xh + ((size_t)s << 7) + c0);
            }
            int lim = min(8, cnt - j0);
            #pragma unroll
            for (int u = 0; u < 8; ++u) {
                if (u < lim) {   // wave-uniform predicate
                    float m0 = fmaxf(__fmaf_rn(aa[u], ew0, eb0) + (float)g[u].x, 0.f) + 1e-7f;
                    float m1 = fmaxf(__fmaf_rn(aa[u], ew1, eb1) + (float)g[u].y, 0.f) + 1e-7f;
                    float e0 = __expf(m0 * tc), e1 = __expf(m1 * tc);
                    den0 += e0; num0 = __fmaf_rn(e0, m0, num0);
                    den1 += e1; num1 = __fmaf_rn(e1, m1, num1);
                }
            }
        }
    }
    h2 sv2 = *(const h2*)(xh + ((size_t)d << 7) + c0);
    float o0 = num0 / fmaxf(den0, 1e-16f) + (float)sv2.x;
    float o1 = num1 / fmaxf(den1, 1e-16f) + (float)sv2.y;
    h2 ov; ov.x = (_Float16)o0; ov.y = (_Float16)o1;
    *(h2*)(oh + ((size_t)d << 7) + c0) = ov;
}

// ------------- fp16 MFMA GEMM (node linear only): C half = A @ Bt^T + bias -------------
__global__ __launch_bounds__(256) void gemm_mfma(
    const _Float16* __restrict__ A, const _Float16* __restrict__ Bt,
    const float* __restrict__ bias, _Float16* __restrict__ C,
    int M, int N, int K)
{
    constexpr int LDA = 40;
    __shared__ _Float16 As[64 * LDA];
    __shared__ _Float16 Bs[128 * LDA];
    int t = threadIdx.x;
    int row0 = blockIdx.y * 64;
    int col0 = blockIdx.x * 128;
    int w = t >> 6, lane = t & 63;
    int wm = w & 1, wn = w >> 1;
    int q = lane >> 4, l16 = lane & 15;
    f4 acc[2][4];
    #pragma unroll
    for (int i = 0; i < 2; ++i)
        #pragma unroll
        for (int j = 0; j < 4; ++j)
            acc[i][j] = (f4){0.f, 0.f, 0.f, 0.f};

    for (int k0 = 0; k0 < K; k0 += 32) {
        {
            int r = t >> 2, seg = t & 3;
            *(float4*)&As[r * LDA + seg * 8] =
                *(const float4*)(A + (size_t)(row0 + r) * K + k0 + seg * 8);
        }
        #pragma unroll
        for (int i = 0; i < 2; ++i) {
            int idx = t + i * 256;
            int r = idx >> 2, seg = idx & 3;
            *(float4*)&Bs[r * LDA + seg * 8] =
                *(const float4*)(Bt + (size_t)(col0 + r) * K + k0 + seg * 8);
        }
        __syncthreads();
        half8 af[2], bf[4];
        #pragma unroll
        for (int i = 0; i < 2; ++i)
            af[i] = *(const half8*)&As[(wm * 32 + i * 16 + l16) * LDA + q * 8];
        #pragma unroll
        for (int j = 0; j < 4; ++j)
            bf[j] = *(const half8*)&Bs[(wn * 64 + j * 16 + l16) * LDA + q * 8];
        #pragma unroll
        for (int i = 0; i < 2; ++i)
            #pragma unroll
            for (int j = 0; j < 4; ++j)
                acc[i][j] = __builtin_amdgcn_mfma_f32_16x16x32_f16(af[i], bf[j], acc[i][j], 0, 0, 0);
        __syncthreads();
    }
    #pragma unroll
    for (int j = 0; j < 4; ++j) {
        int col = col0 + wn * 64 + j * 16 + l16;
        float bv = bias[col];
        #pragma unroll
        for (int i = 0; i < 2; ++i) {
            int rbase = row0 + wm * 32 + i * 16 + q * 4;
            #pragma unroll
            for (int rg = 0; rg < 4; ++rg)
                C[(size_t)(rbase + rg) * N + col] = (_Float16)(acc[i][j][rg] + bv);
        }
    }
}

// ------------- fused: lin1 -> LN1 -> ReLU -> lin2 (+bias) [+res] -> h; blockLN -> ReLU -> xout -------------
// 64 rows per block, 256 threads = 4 waves (wm in M x2, wn in N x2).
template<int RES>
__global__ __launch_bounds__(256) void mlp_fused(
    const _Float16* __restrict__ Ain,    // [M][128] half (agg out)
    const _Float16* __restrict__ w1t,    // [256][128] half
    const float* __restrict__ b1,        // [256]
    const float* __restrict__ g1, const float* __restrict__ bt1,  // LN1 [256]
    const _Float16* __restrict__ w2t,    // [128][256] half
    const float* __restrict__ b2,        // [128]
    float* __restrict__ h,               // [M][128] fp32 (out; read for RES)
    const float* __restrict__ bg, const float* __restrict__ bb,   // block LN [128]
    _Float16* __restrict__ xout)         // [M][128] half
{
    constexpr int LDA = 136;  // halves, 272B = 68 words (bank-rotating)
    constexpr int LDB = 40;
    constexpr int LDM = 264;
    __shared__ _Float16 As[64 * LDA];
    __shared__ _Float16 Bs[256 * LDB];
    __shared__ _Float16 midh[64 * LDM];
    __shared__ float ssum[64][2], ssum2[64][2];
    int t = threadIdx.x;
    int row0 = blockIdx.x * 64;
    int w = t >> 6, lane = t & 63;
    int wm = w & 1, wn = w >> 1;
    int q = lane >> 4, l16 = lane & 15;

    // stage A fully: 64 rows x 128 halves (16 chunks of 16B per row)
    #pragma unroll
    for (int p = 0; p < 4; ++p) {
        int idx = t + p * 256;
        int r = idx >> 4, seg = idx & 15;
        *(float4*)&As[r * LDA + seg * 8] =
            *(const float4*)(Ain + (size_t)(row0 + r) * 128 + seg * 8);
    }

    // ---- lin1: mid[64][256] = A @ w1t^T ----
    f4 acc[2][8];
    #pragma unroll
    for (int i = 0; i < 2; ++i)
        #pragma unroll
        for (int j = 0; j < 8; ++j)
            acc[i][j] = (f4){0.f, 0.f, 0.f, 0.f};
    for (int k0 = 0; k0 < 128; k0 += 32) {
        #pragma unroll
        for (int p = 0; p < 4; ++p) {       // stage B1 tile [256][32]
            int idx = t + p * 256;
            int r = idx >> 2, seg = idx & 3;
            *(float4*)&Bs[r * LDB + seg * 8] =
                *(const float4*)(w1t + (size_t)r * 128 + k0 + seg * 8);
        }
        __syncthreads();
        half8 af[2], bf[8];
        #pragma unroll
        for (int i = 0; i < 2; ++i)
            af[i] = *(const half8*)&As[(wm * 32 + i * 16 + l16) * LDA + k0 + q * 8];
        #pragma unroll
        for (int j = 0; j < 8; ++j)
            bf[j] = *(const half8*)&Bs[(wn * 128 + j * 16 + l16) * LDB + q * 8];
        #pragma unroll
        for (int i = 0; i < 2; ++i)
            #pragma unroll
            for (int j = 0; j < 8; ++j)
                acc[i][j] = __builtin_amdgcn_mfma_f32_16x16x32_f16(af[i], bf[j], acc[i][j], 0, 0, 0);
        __syncthreads();
    }

    // ---- bias + LN1 stats (rows of 256) in registers ----
    float b1v[8], g1v[8], bt1v[8];
    #pragma unroll
    for (int j = 0; j < 8; ++j) {
        int col = wn * 128 + j * 16 + l16;
        b1v[j] = b1[col]; g1v[j] = g1[col]; bt1v[j] = bt1[col];
    }
    float vals[2][8][4];
    #pragma unroll
    for (int i = 0; i < 2; ++i)
        #pragma unroll
        for (int j = 0; j < 8; ++j)
            #pragma unroll
            for (int rg = 0; rg < 4; ++rg)
                vals[i][j][rg] = acc[i][j][rg] + b1v[j];
    #pragma unroll
    for (int i = 0; i < 2; ++i) {
        #pragma unroll
        for (int rg = 0; rg < 4; ++rg) {
            float ps = 0.f, ps2 = 0.f;
            #pragma unroll
            for (int j = 0; j < 8; ++j) { float v = vals[i][j][rg]; ps += v; ps2 += v * v; }
            #pragma unroll
            for (int off = 1; off < 16; off <<= 1) {
                ps  += __shfl_xor(ps,  off, 16);
                ps2 += __shfl_xor(ps2, off, 16);
            }
            if (l16 == 0) {
                int row = wm * 32 + i * 16 + q * 4 + rg;
                ssum[row][wn] = ps; ssum2[row][wn] = ps2;
            }
        }
    }
    __syncthreads();
    #pragma unroll
    for (int i = 0; i < 2; ++i) {
        #pragma unroll
        for (int rg = 0; rg < 4; ++rg) {
            int row = wm * 32 + i * 16 + q * 4 + rg;
            float S = ssum[row][0] + ssum[row][1];
            float S2 = ssum2[row][0] + ssum2[row][1];
            float mu = S * (1.0f / 256.0f);
            float var = S2 * (1.0f / 256.0f) - mu * mu;
            float rstd = rsqrtf(var + 1e-5f);
            #pragma unroll
            for (int j = 0; j < 8; ++j) {
                int col = wn * 128 + j * 16 + l16;
                float o = fmaxf((vals[i][j][rg] - mu) * rstd * g1v[j] + bt1v[j], 0.f);
                midh[row * LDM + col] = (_Float16)o;
            }
        }
    }
    __syncthreads();

    // ---- lin2: out[64][128] = mid @ w2t^T ----
    f4 acc2[2][4];
    #pragma unroll
    for (int i = 0; i < 2; ++i)
        #pragma unroll
        for (int j = 0; j < 4; ++j)
            acc2[i][j] = (f4){0.f, 0.f, 0.f, 0.f};
    for (int k0 = 0; k0 < 256; k0 += 32) {
        #pragma unroll
        for (int p = 0; p < 2; ++p) {       // stage B2 tile [128][32]
            int idx = t + p * 256;
            int r = idx >> 2, seg = idx & 3;
            *(float4*)&Bs[r * LDB + seg * 8] =
                *(const float4*)(w2t + (size_t)r * 256 + k0 + seg * 8);
        }
        __syncthreads();
        half8 af2[2], bf2[4];
        #pragma unroll
        for (int i = 0; i < 2; ++i)
            af2[i] = *(const half8*)&midh[(wm * 32 + i * 16 + l16) * LDM + k0 + q * 8];
        #pragma unroll
        for (int j = 0; j < 4; ++j)
            bf2[j] = *(const half8*)&Bs[(wn * 64 + j * 16 + l16) * LDB + q * 8];
        #pragma unroll
        for (int i = 0; i < 2; ++i)
            #pragma unroll
            for (int j = 0; j < 4; ++j)
                acc2[i][j] = __builtin_amdgcn_mfma_f32_16x16x32_f16(af2[i], bf2[j], acc2[i][j], 0, 0, 0);
        __syncthreads();
    }

    // ---- epilogue: bias (+res) -> h; block LN + ReLU -> xout ----
    float b2v[4], bgv[4], bbv[4];
    #pragma unroll
    for (int j = 0; j < 4; ++j) {
        int col = wn * 64 + j * 16 + l16;
        b2v[j] = b2[col]; bgv[j] = bg[col]; bbv[j] = bb[col];
    }
    float ov[2][4][4];
    #pragma unroll
    for (int i = 0; i < 2; ++i) {
        #pragma unroll
        for (int rg = 0; rg < 4; ++rg) {
            int row = wm * 32 + i * 16 + q * 4 + rg;
            #pragma unroll
            for (int j = 0; j < 4; ++j) {
                int col = wn * 64 + j * 16 + l16;
                float v = acc2[i][j][rg] + b2v[j];
                size_t gidx = (size_t)(row0 + row) * 128 + col;
                if (RES) v += h[gidx];
                h[gidx] = v;
                ov[i][j][rg] = v;
            }
        }
    }
    #pragma unroll
    for (int i = 0; i < 2; ++i) {
        #pragma unroll
        for (int rg = 0; rg < 4; ++rg) {
            float ps = 0.f, ps2 = 0.f;
            #pragma unroll
            for (int j = 0; j < 4; ++j) { float v = ov[i][j][rg]; ps += v; ps2 += v * v; }
            #pragma unroll
            for (int off = 1; off < 16; off <<= 1) {
                ps  += __shfl_xor(ps,  off, 16);
                ps2 += __shfl_xor(ps2, off, 16);
            }
            if (l16 == 0) {
                int row = wm * 32 + i * 16 + q * 4 + rg;
                ssum[row][wn] = ps; ssum2[row][wn] = ps2;
            }
        }
    }
    __syncthreads();
    #pragma unroll
    for (int i = 0; i < 2; ++i) {
        #pragma unroll
        for (int rg = 0; rg < 4; ++rg) {
            int row = wm * 32 + i * 16 + q * 4 + rg;
            float S = ssum[row][0] + ssum[row][1];
            float S2 = ssum2[row][0] + ssum2[row][1];
            float mu = S * (1.0f / 128.0f);
            float var = S2 * (1.0f / 128.0f) - mu * mu;
            float rstd = rsqrtf(var + 1e-5f);
            #pragma unroll
            for (int j = 0; j < 4; ++j) {
                int col = wn * 64 + j * 16 + l16;
                float o = fmaxf((ov[i][j][rg] - mu) * rstd * bgv[j] + bbv[j], 0.f);
                xout[(size_t)(row0 + row) * 128 + col] = (_Float16)o;
            }
        }
    }
}

// ------------- mean pool over sorted batch (half input) -------------
__global__ __launch_bounds__(128) void pool_kernel(
    const _Float16* __restrict__ f, const int* __restrict__ batch, float* __restrict__ pooled)
{
    int g = blockIdx.x;
    int chunk = blockIdx.y;
    int c = threadIdx.x;
    int s = lower_bound_dev(batch, NN, g);
    int e = lower_bound_dev(batch, NN, g + 1);
    int len = e - s;
    if (len <= 0) return;
    int nch = gridDim.y;
    int per = (len + nch - 1) / nch;
    int cs = s + chunk * per;
    int ce = min(cs + per, e);
    if (cs >= ce) return;
    float acc = 0.f;
    for (int n = cs; n < ce; ++n) acc += (float)f[(size_t)n * HH + c];
    atomicAdd(&pooled[g * HH + c], acc);
}

// ------------- MLP head -------------
__global__ __launch_bounds__(128) void head_kernel(
    const float* __restrict__ pooled, const int* __restrict__ batch,
    const float* __restrict__ hw1, const float* __restrict__ hb1,
    const float* __restrict__ hw2, const float* __restrict__ hb2,
    const float* __restrict__ hw3, const float* __restrict__ hb3,
    float* __restrict__ out)
{
    __shared__ float p[HH];
    __shared__ float o1[64];
    __shared__ float o2[32];
    int g = blockIdx.x;
    int t = threadIdx.x;
    int s = lower_bound_dev(batch, NN, g);
    int e = lower_bound_dev(batch, NN, g + 1);
    float cnt = fmaxf((float)(e - s), 1.0f);
    p[t] = pooled[g * HH + t] / cnt;
    __syncthreads();
    if (t < 64) {
        float acc = hb1[t];
        for (int k = 0; k < HH; ++k) acc += p[k] * hw1[k * 64 + t];
        o1[t] = fmaxf(acc, 0.f);
    }
    __syncthreads();
    if (t < 32) {
        float acc = hb2[t];
        for (int k = 0; k < 64; ++k) acc += o1[k] * hw2[k * 32 + t];
        o2[t] = fmaxf(acc, 0.f);
    }
    __syncthreads();
    if (t == 0) {
        float acc = hb3[0];
        for (int k = 0; k < 32; ++k) acc += o2[k] * hw3[k];
        out[g] = acc;
    }
}

extern "C" void kernel_launch(void* const* d_in, const int* in_sizes, int n_in,
                              void* d_out, int out_size, void* d_ws, size_t ws_size,
                              hipStream_t stream)
{
    const float* x      = (const float*)d_in[0];
    const float* eattr  = (const float*)d_in[1];
    const float* node_w = (const float*)d_in[2];
    const float* node_b = (const float*)d_in[3];
    const float* edge_w = (const float*)d_in[4];
    const float* edge_b = (const float*)d_in[5];
    const float* tptr   = (const float*)d_in[6];
    const float* lin1_w = (const float*)d_in[7];
    const float* lin1_b = (const float*)d_in[8];
    const float* ln1_g  = (const float*)d_in[9];
    const float* ln1_bt = (const float*)d_in[10];
    const float* lin2_w = (const float*)d_in[11];
    const float* lin2_b = (const float*)d_in[12];
    const float* blk_g  = (const float*)d_in[13];
    const float* blk_b  = (const float*)d_in[14];
    const float* hw1    = (const float*)d_in[15];
    const float* hb1    = (const float*)d_in[16];
    const float* hw2    = (const float*)d_in[17];
    const float* hb2    = (const float*)d_in[18];
    const float* hw3    = (const float*)d_in[19];
    const float* hb3    = (const float*)d_in[20];
    const int*   eidx   = (const int*)d_in[21];
    const int*   batch  = (const int*)d_in[22];
    const int* src = eidx;
    const int* dst = eidx + NE;
    float* out = (float*)d_out;

    char* ws = (char*)d_ws;
    size_t off = 0;
    auto carve = [&](size_t bytes) -> char* {
        char* p = ws + off;
        off = (off + bytes + 255) & ~(size_t)255;
        return p;
    };
    float*    h      = (float*)carve((size_t)NN * HH * 4);
    _Float16* xh_in  = (_Float16*)carve((size_t)NX * 2);
    _Float16* xnh    = (_Float16*)carve((size_t)NN * HH * 2);
    _Float16* oh     = (_Float16*)carve((size_t)NN * HH * 2);
    _Float16* rh     = (_Float16*)carve((size_t)NN * HH * 2);
    _Float16* nwt    = (_Float16*)carve((size_t)16384 * 2);
    _Float16* w1t    = (_Float16*)carve((size_t)98304 * 2);
    _Float16* w2t    = (_Float16*)carve((size_t)98304 * 2);
    int*      counts = (int*)carve((size_t)NN * 4);
    int*      rowp   = (int*)carve((size_t)(NN + 1) * 4);
    int*      cursor = (int*)carve((size_t)NN * 4);
    int*      src_s  = (int*)carve((size_t)NE * 4);
    float*    attr_s = (float*)carve((size_t)NE * 4);
    float*    pooled = (float*)carve((size_t)NG * HH * 4);

    hipMemsetAsync(counts, 0, (size_t)NN * 4, stream);
    hipMemsetAsync(pooled, 0, (size_t)NG * HH * 4, stream);

    {
        int total = NX + 16384 + 98304 + 98304;
        convert_kernel<<<(total + 255) / 256, 256, 0, stream>>>(
            x, node_w, lin1_w, lin2_w, xh_in, nwt, w1t, w2t);
    }
    count_kernel<<<(NE + 255) / 256, 256, 0, stream>>>(dst, counts);
    scan_kernel<<<1, 1024, 0, stream>>>(counts, rowp, cursor);
    fill_kernel<<<(NE + 255) / 256, 256, 0, stream>>>(src, dst, eattr, cursor, src_s, attr_s);

    // node linear: xnh = half(x @ node_w + node_b)
    gemm_mfma<<<dim3(1, NN / 64), 256, 0, stream>>>(xh_in, nwt, node_b, xnh, NN, HH, DIM_IN);

    // layer 0 (no residual; post-LN uses blk[1] to produce layer-1 conv input)
    agg_kernel<<<NN / 4, 256, 0, stream>>>(xnh, rowp, src_s, attr_s, edge_w, edge_b, tptr, 0, oh);
    mlp_fused<0><<<NN / 64, 256, 0, stream>>>(
        oh, w1t, lin1_b, ln1_g, ln1_bt, w2t, lin2_b,
        h, blk_g + 1 * HH, blk_b + 1 * HH, xnh);
    // layer 1 (residual; post-LN uses blk[2])
    agg_kernel<<<NN / 4, 256, 0, stream>>>(xnh, rowp, src_s, attr_s, edge_w, edge_b, tptr, 1, oh);
    mlp_fused<1><<<NN / 64, 256, 0, stream>>>(
        oh, w1t + 32768, lin1_b + HH2, ln1_g + HH2, ln1_bt + HH2, w2t + 32768, lin2_b + HH,
        h, blk_g + 2 * HH, blk_b + 2 * HH, xnh);
    // layer 2 (residual; final LN uses blk[0] -> rh for pooling)
    agg_kernel<<<NN / 4, 256, 0, stream>>>(xnh, rowp, src_s, attr_s, edge_w, edge_b, tptr, 2, oh);
    mlp_fused<1><<<NN / 64, 256, 0, stream>>>(
        oh, w1t + 2 * 32768, lin1_b + 2 * HH2, ln1_g + 2 * HH2, ln1_bt + 2 * HH2,
        w2t + 2 * 32768, lin2_b + 2 * HH,
        h, blk_g, blk_b, rh);

    pool_kernel<<<dim3(NG, 8), 128, 0, stream>>>(rh, batch, pooled);
    head_kernel<<<NG, 128, 0, stream>>>(pooled, batch, hw1, hb1, hw2, hb2, hw3, hb3, out);
}

// Round 4
// 393.999 us; speedup vs baseline: 2.2976x; 1.1607x over previous
//
#include <hip/hip_runtime.h>
#include <math.h>

#define NN 40000
#define NE 600000
#define NG 64
#define DIM_IN 128
#define HH 128
#define HH2 256

using half8 = __attribute__((ext_vector_type(8))) _Float16;
using half4 = __attribute__((ext_vector_type(4))) _Float16;
using h2    = __attribute__((ext_vector_type(2))) _Float16;
using f4    = __attribute__((ext_vector_type(4))) float;

__device__ __forceinline__ int lower_bound_dev(const int* a, int n, int key) {
    int lo = 0, hi = n;
    while (lo < hi) { int mid = (lo + hi) >> 1; if (a[mid] < key) lo = mid + 1; else hi = mid; }
    return lo;
}

// ---------------- weight/input fp32 -> fp16 conversion (+ B^T layouts) ----------------
#define NX (NN*DIM_IN)
#define NX4 (NX/4)
__global__ void convert_kernel(const float* __restrict__ x, const float* __restrict__ node_w,
                               const float* __restrict__ lin1_w, const float* __restrict__ lin2_w,
                               _Float16* __restrict__ xh, _Float16* __restrict__ nwt,
                               _Float16* __restrict__ w1t, _Float16* __restrict__ w2t)
{
    int id = blockIdx.x * blockDim.x + threadIdx.x;
    if (id < NX4) {
        float4 v = *(const float4*)(x + (size_t)id * 4);
        half4 o; o.x = (_Float16)v.x; o.y = (_Float16)v.y; o.z = (_Float16)v.z; o.w = (_Float16)v.w;
        *(half4*)(xh + (size_t)id * 4) = o;
        return;
    }
    id -= NX4;
    if (id < 16384) { int n = id >> 7, k = id & 127; nwt[id] = (_Float16)node_w[k*128 + n]; return; }
    id -= 16384;
    if (id < 98304) {
        int l = id >> 15, r = id & 32767;
        int n = r >> 7, k = r & 127;
        w1t[id] = (_Float16)lin1_w[l*32768 + k*256 + n];
        return;
    }
    id -= 98304;
    if (id < 98304) {
        int l = id >> 15, r = id & 32767;
        int n = r >> 8, k = r & 255;
        w2t[id] = (_Float16)lin2_w[l*32768 + k*128 + n];
    }
}

// ---------------- CSR build: count+rank, 3-stage scan, no-atomic fill ----------------
__global__ void count_rank_kernel(const int* __restrict__ dst, int* __restrict__ counts,
                                  int* __restrict__ rank) {
    int e = blockIdx.x * blockDim.x + threadIdx.x;
    if (e < NE) rank[e] = atomicAdd(&counts[dst[e]], 1);   // rank write coalesced
}

__global__ __launch_bounds__(1024) void scanA_kernel(const int* __restrict__ counts,
                                                     int* __restrict__ tmp, int* __restrict__ btot) {
    __shared__ int wpre[16];
    int t = threadIdx.x, lane = t & 63, wid = t >> 6;
    int i = blockIdx.x * 1024 + t;
    int v = (i < NN) ? counts[i] : 0;
    int s = v;
    #pragma unroll
    for (int off = 1; off < 64; off <<= 1) {
        int u = __shfl_up(s, off, 64);
        if (lane >= off) s += u;
    }
    if (lane == 63) wpre[wid] = s;
    __syncthreads();
    if (t == 0) {
        int run = 0;
        #pragma unroll
        for (int j = 0; j < 16; ++j) { int xv = wpre[j]; wpre[j] = run; run += xv; }
        btot[blockIdx.x] = run;
    }
    __syncthreads();
    if (i < NN) tmp[i] = s + wpre[wid];
}

__global__ __launch_bounds__(64) void scanB_kernel(const int* __restrict__ btot,
                                                   int* __restrict__ boff, int nb) {
    int t = threadIdx.x;
    int v = (t < nb) ? btot[t] : 0;
    int s = v;
    #pragma unroll
    for (int off = 1; off < 64; off <<= 1) {
        int u = __shfl_up(s, off, 64);
        if (t >= off) s += u;
    }
    if (t < nb) boff[t] = s - v;   // exclusive
}

__global__ __launch_bounds__(1024) void scanC_kernel(const int* __restrict__ tmp,
                                                     const int* __restrict__ boff,
                                                     int* __restrict__ rowp) {
    int i = blockIdx.x * 1024 + threadIdx.x;
    if (i < NN) rowp[i + 1] = tmp[i] + boff[blockIdx.x];
    if (i == 0) rowp[0] = 0;
}

__global__ void fill2_kernel(const int* __restrict__ src, const int* __restrict__ dst,
                             const float* __restrict__ eattr, const int* __restrict__ rowp,
                             const int* __restrict__ rank, int2* __restrict__ rec) {
    int e = blockIdx.x * blockDim.x + threadIdx.x;
    if (e < NE) {
        int pos = rowp[dst[e]] + rank[e];
        rec[pos] = make_int2(src[e], __float_as_int(eattr[e]));   // one 8B scatter, no atomic
    }
}

// ------------- scatter-softmax aggregation: double-buffered prefetch-8 gathers -------------
__global__ __launch_bounds__(256) void agg_kernel(
    const _Float16* __restrict__ xh,
    const int* __restrict__ row_ptr,
    const int2* __restrict__ rec,
    const float* __restrict__ ew, const float* __restrict__ eb,
    const float* __restrict__ tptr, int layer,
    _Float16* __restrict__ oh)
{
    int d = blockIdx.x * 4 + (threadIdx.x >> 6);
    int lane = threadIdx.x & 63;
    int c0 = 2 * lane;
    float tc = tptr[layer];
    float ew0 = ew[c0], eb0 = eb[c0];
    float ew1 = ew[c0 + 1], eb1 = eb[c0 + 1];
    int beg = row_ptr[d], end = row_ptr[d + 1];
    float den0 = 0.f, num0 = 0.f, den1 = 0.f, num1 = 0.f;
    for (int base = beg; base < end; base += 64) {
        int cnt = min(64, end - base);
        int2 mv = rec[base + min(lane, cnt - 1)];   // 64 edges' meta in one coalesced 8B load
        int sv = mv.x;
        float av = __int_as_float(mv.y);
        h2 gA[8], gB[8]; float aA[8], aB[8];
        auto issue = [&](h2 (&g)[8], float (&aa)[8], int j0) {
            #pragma unroll
            for (int u = 0; u < 8; ++u) {
                int jj = min(j0 + u, cnt - 1);
                int s = __shfl(sv, jj, 64);
                aa[u] = __shfl(av, jj, 64);
                g[u] = *(const h2*)(xh + ((size_t)s << 7) + c0);
            }
        };
        auto consume = [&](h2 (&g)[8], float (&aa)[8], int j0) {
            int lim = min(8, cnt - j0);
            #pragma unroll
            for (int u = 0; u < 8; ++u) {
                if (u < lim) {   // wave-uniform
                    float m0 = fmaxf(__fmaf_rn(aa[u], ew0, eb0) + (float)g[u].x, 0.f) + 1e-7f;
                    float m1 = fmaxf(__fmaf_rn(aa[u], ew1, eb1) + (float)g[u].y, 0.f) + 1e-7f;
                    float e0 = __expf(m0 * tc), e1 = __expf(m1 * tc);
                    den0 += e0; num0 = __fmaf_rn(e0, m0, num0);
                    den1 += e1; num1 = __fmaf_rn(e1, m1, num1);
                }
            }
        };
        issue(gA, aA, 0);
        for (int j0 = 0; j0 < cnt; j0 += 16) {
            if (j0 + 8 < cnt)  issue(gB, aB, j0 + 8);
            consume(gA, aA, j0);
            if (j0 + 16 < cnt) issue(gA, aA, j0 + 16);
            if (j0 + 8 < cnt)  consume(gB, aB, j0 + 8);
        }
    }
    h2 sv2 = *(const h2*)(xh + ((size_t)d << 7) + c0);
    float o0 = num0 / fmaxf(den0, 1e-16f) + (float)sv2.x;
    float o1 = num1 / fmaxf(den1, 1e-16f) + (float)sv2.y;
    h2 ov; ov.x = (_Float16)o0; ov.y = (_Float16)o1;
    *(h2*)(oh + ((size_t)d << 7) + c0) = ov;
}

// ------------- fp16 MFMA GEMM (node linear only): C half = A @ Bt^T + bias -------------
__global__ __launch_bounds__(256) void gemm_mfma(
    const _Float16* __restrict__ A, const _Float16* __restrict__ Bt,
    const float* __restrict__ bias, _Float16* __restrict__ C,
    int M, int N, int K)
{
    constexpr int LDA = 40;
    __shared__ _Float16 As[64 * LDA];
    __shared__ _Float16 Bs[128 * LDA];
    int t = threadIdx.x;
    int row0 = blockIdx.y * 64;
    int col0 = blockIdx.x * 128;
    int w = t >> 6, lane = t & 63;
    int wm = w & 1, wn = w >> 1;
    int q = lane >> 4, l16 = lane & 15;
    f4 acc[2][4];
    #pragma unroll
    for (int i = 0; i < 2; ++i)
        #pragma unroll
        for (int j = 0; j < 4; ++j)
            acc[i][j] = (f4){0.f, 0.f, 0.f, 0.f};

    for (int k0 = 0; k0 < K; k0 += 32) {
        {
            int r = t >> 2, seg = t & 3;
            *(float4*)&As[r * LDA + seg * 8] =
                *(const float4*)(A + (size_t)(row0 + r) * K + k0 + seg * 8);
        }
        #pragma unroll
        for (int i = 0; i < 2; ++i) {
            int idx = t + i * 256;
            int r = idx >> 2, seg = idx & 3;
            *(float4*)&Bs[r * LDA + seg * 8] =
                *(const float4*)(Bt + (size_t)(col0 + r) * K + k0 + seg * 8);
        }
        __syncthreads();
        half8 af[2], bf[4];
        #pragma unroll
        for (int i = 0; i < 2; ++i)
            af[i] = *(const half8*)&As[(wm * 32 + i * 16 + l16) * LDA + q * 8];
        #pragma unroll
        for (int j = 0; j < 4; ++j)
            bf[j] = *(const half8*)&Bs[(wn * 64 + j * 16 + l16) * LDA + q * 8];
        #pragma unroll
        for (int i = 0; i < 2; ++i)
            #pragma unroll
            for (int j = 0; j < 4; ++j)
                acc[i][j] = __builtin_amdgcn_mfma_f32_16x16x32_f16(af[i], bf[j], acc[i][j], 0, 0, 0);
        __syncthreads();
    }
    #pragma unroll
    for (int j = 0; j < 4; ++j) {
        int col = col0 + wn * 64 + j * 16 + l16;
        float bv = bias[col];
        #pragma unroll
        for (int i = 0; i < 2; ++i) {
            int rbase = row0 + wm * 32 + i * 16 + q * 4;
            #pragma unroll
            for (int rg = 0; rg < 4; ++rg)
                C[(size_t)(rbase + rg) * N + col] = (_Float16)(acc[i][j][rg] + bv);
        }
    }
}

// ------------- fused: lin1 -> LN1 -> ReLU -> lin2 (+bias) [+res] -> h; blockLN -> ReLU -> xout -------------
template<int RES>
__global__ __launch_bounds__(256) void mlp_fused(
    const _Float16* __restrict__ Ain,
    const _Float16* __restrict__ w1t,
    const float* __restrict__ b1,
    const float* __restrict__ g1, const float* __restrict__ bt1,
    const _Float16* __restrict__ w2t,
    const float* __restrict__ b2,
    float* __restrict__ h,
    const float* __restrict__ bg, const float* __restrict__ bb,
    _Float16* __restrict__ xout)
{
    constexpr int LDA = 136;
    constexpr int LDB = 40;
    constexpr int LDM = 264;
    __shared__ _Float16 As[64 * LDA];
    __shared__ _Float16 Bs[256 * LDB];
    __shared__ _Float16 midh[64 * LDM];
    __shared__ float ssum[64][2], ssum2[64][2];
    int t = threadIdx.x;
    int row0 = blockIdx.x * 64;
    int w = t >> 6, lane = t & 63;
    int wm = w & 1, wn = w >> 1;
    int q = lane >> 4, l16 = lane & 15;

    #pragma unroll
    for (int p = 0; p < 4; ++p) {
        int idx = t + p * 256;
        int r = idx >> 4, seg = idx & 15;
        *(float4*)&As[r * LDA + seg * 8] =
            *(const float4*)(Ain + (size_t)(row0 + r) * 128 + seg * 8);
    }

    f4 acc[2][8];
    #pragma unroll
    for (int i = 0; i < 2; ++i)
        #pragma unroll
        for (int j = 0; j < 8; ++j)
            acc[i][j] = (f4){0.f, 0.f, 0.f, 0.f};
    for (int k0 = 0; k0 < 128; k0 += 32) {
        #pragma unroll
        for (int p = 0; p < 4; ++p) {
            int idx = t + p * 256;
            int r = idx >> 2, seg = idx & 3;
            *(float4*)&Bs[r * LDB + seg * 8] =
                *(const float4*)(w1t + (size_t)r * 128 + k0 + seg * 8);
        }
        __syncthreads();
        half8 af[2], bf[8];
        #pragma unroll
        for (int i = 0; i < 2; ++i)
            af[i] = *(const half8*)&As[(wm * 32 + i * 16 + l16) * LDA + k0 + q * 8];
        #pragma unroll
        for (int j = 0; j < 8; ++j)
            bf[j] = *(const half8*)&Bs[(wn * 128 + j * 16 + l16) * LDB + q * 8];
        #pragma unroll
        for (int i = 0; i < 2; ++i)
            #pragma unroll
            for (int j = 0; j < 8; ++j)
                acc[i][j] = __builtin_amdgcn_mfma_f32_16x16x32_f16(af[i], bf[j], acc[i][j], 0, 0, 0);
        __syncthreads();
    }

    float b1v[8], g1v[8], bt1v[8];
    #pragma unroll
    for (int j = 0; j < 8; ++j) {
        int col = wn * 128 + j * 16 + l16;
        b1v[j] = b1[col]; g1v[j] = g1[col]; bt1v[j] = bt1[col];
    }
    float vals[2][8][4];
    #pragma unroll
    for (int i = 0; i < 2; ++i)
        #pragma unroll
        for (int j = 0; j < 8; ++j)
            #pragma unroll
            for (int rg = 0; rg < 4; ++rg)
                vals[i][j][rg] = acc[i][j][rg] + b1v[j];
    #pragma unroll
    for (int i = 0; i < 2; ++i) {
        #pragma unroll
        for (int rg = 0; rg < 4; ++rg) {
            float ps = 0.f, ps2 = 0.f;
            #pragma unroll
            for (int j = 0; j < 8; ++j) { float v = vals[i][j][rg]; ps += v; ps2 += v * v; }
            #pragma unroll
            for (int off = 1; off < 16; off <<= 1) {
                ps  += __shfl_xor(ps,  off, 16);
                ps2 += __shfl_xor(ps2, off, 16);
            }
            if (l16 == 0) {
                int row = wm * 32 + i * 16 + q * 4 + rg;
                ssum[row][wn] = ps; ssum2[row][wn] = ps2;
            }
        }
    }
    __syncthreads();
    #pragma unroll
    for (int i = 0; i < 2; ++i) {
        #pragma unroll
        for (int rg = 0; rg < 4; ++rg) {
            int row = wm * 32 + i * 16 + q * 4 + rg;
            float S = ssum[row][0] + ssum[row][1];
            float S2 = ssum2[row][0] + ssum2[row][1];
            float mu = S * (1.0f / 256.0f);
            float var = S2 * (1.0f / 256.0f) - mu * mu;
            float rstd = rsqrtf(var + 1e-5f);
            #pragma unroll
            for (int j = 0; j < 8; ++j) {
                int col = wn * 128 + j * 16 + l16;
                float o = fmaxf((vals[i][j][rg] - mu) * rstd * g1v[j] + bt1v[j], 0.f);
                midh[row * LDM + col] = (_Float16)o;
            }
        }
    }
    __syncthreads();

    f4 acc2[2][4];
    #pragma unroll
    for (int i = 0; i < 2; ++i)
        #pragma unroll
        for (int j = 0; j < 4; ++j)
            acc2[i][j] = (f4){0.f, 0.f, 0.f, 0.f};
    for (int k0 = 0; k0 < 256; k0 += 32) {
        #pragma unroll
        for (int p = 0; p < 2; ++p) {
            int idx = t + p * 256;
            int r = idx >> 2, seg = idx & 3;
            *(float4*)&Bs[r * LDB + seg * 8] =
                *(const float4*)(w2t + (size_t)r * 256 + k0 + seg * 8);
        }
        __syncthreads();
        half8 af2[2], bf2[4];
        #pragma unroll
        for (int i = 0; i < 2; ++i)
            af2[i] = *(const half8*)&midh[(wm * 32 + i * 16 + l16) * LDM + k0 + q * 8];
        #pragma unroll
        for (int j = 0; j < 4; ++j)
            bf2[j] = *(const half8*)&Bs[(wn * 64 + j * 16 + l16) * LDB + q * 8];
        #pragma unroll
        for (int i = 0; i < 2; ++i)
            #pragma unroll
            for (int j = 0; j < 4; ++j)
                acc2[i][j] = __builtin_amdgcn_mfma_f32_16x16x32_f16(af2[i], bf2[j], acc2[i][j], 0, 0, 0);
        __syncthreads();
    }

    float b2v[4], bgv[4], bbv[4];
    #pragma unroll
    for (int j = 0; j < 4; ++j) {
        int col = wn * 64 + j * 16 + l16;
        b2v[j] = b2[col]; bgv[j] = bg[col]; bbv[j] = bb[col];
    }
    float ov[2][4][4];
    #pragma unroll
    for (int i = 0; i < 2; ++i) {
        #pragma unroll
        for (int rg = 0; rg < 4; ++rg) {
            int row = wm * 32 + i * 16 + q * 4 + rg;
            #pragma unroll
            for (int j = 0; j < 4; ++j) {
                int col = wn * 64 + j * 16 + l16;
                float v = acc2[i][j][rg] + b2v[j];
                size_t gidx = (size_t)(row0 + row) * 128 + col;
                if (RES) v += h[gidx];
                h[gidx] = v;
                ov[i][j][rg] = v;
            }
        }
    }
    #pragma unroll
    for (int i = 0; i < 2; ++i) {
        #pragma unroll
        for (int rg = 0; rg < 4; ++rg) {
            float ps = 0.f, ps2 = 0.f;
            #pragma unroll
            for (int j = 0; j < 4; ++j) { float v = ov[i][j][rg]; ps += v; ps2 += v * v; }
            #pragma unroll
            for (int off = 1; off < 16; off <<= 1) {
                ps  += __shfl_xor(ps,  off, 16);
                ps2 += __shfl_xor(ps2, off, 16);
            }
            if (l16 == 0) {
                int row = wm * 32 + i * 16 + q * 4 + rg;
                ssum[row][wn] = ps; ssum2[row][wn] = ps2;
            }
        }
    }
    __syncthreads();
    #pragma unroll
    for (int i = 0; i < 2; ++i) {
        #pragma unroll
        for (int rg = 0; rg < 4; ++rg) {
            int row = wm * 32 + i * 16 + q * 4 + rg;
            float S = ssum[row][0] + ssum[row][1];
            float S2 = ssum2[row][0] + ssum2[row][1];
            float mu = S * (1.0f / 128.0f);
            float var = S2 * (1.0f / 128.0f) - mu * mu;
            float rstd = rsqrtf(var + 1e-5f);
            #pragma unroll
            for (int j = 0; j < 4; ++j) {
                int col = wn * 64 + j * 16 + l16;
                float o = fmaxf((ov[i][j][rg] - mu) * rstd * bgv[j] + bbv[j], 0.f);
                xout[(size_t)(row0 + row) * 128 + col] = (_Float16)o;
            }
        }
    }
}

// ------------- mean pool over sorted batch (half input) -------------
__global__ __launch_bounds__(128) void pool_kernel(
    const _Float16* __restrict__ f, const int* __restrict__ batch, float* __restrict__ pooled)
{
    int g = blockIdx.x;
    int chunk = blockIdx.y;
    int c = threadIdx.x;
    int s = lower_bound_dev(batch, NN, g);
    int e = lower_bound_dev(batch, NN, g + 1);
    int len = e - s;
    if (len <= 0) return;
    int nch = gridDim.y;
    int per = (len + nch - 1) / nch;
    int cs = s + chunk * per;
    int ce = min(cs + per, e);
    if (cs >= ce) return;
    float acc = 0.f;
    for (int n = cs; n < ce; ++n) acc += (float)f[(size_t)n * HH + c];
    atomicAdd(&pooled[g * HH + c], acc);
}

// ------------- MLP head -------------
__global__ __launch_bounds__(128) void head_kernel(
    const float* __restrict__ pooled, const int* __restrict__ batch,
    const float* __restrict__ hw1, const float* __restrict__ hb1,
    const float* __restrict__ hw2, const float* __restrict__ hb2,
    const float* __restrict__ hw3, const float* __restrict__ hb3,
    float* __restrict__ out)
{
    __shared__ float p[HH];
    __shared__ float o1[64];
    __shared__ float o2[32];
    int g = blockIdx.x;
    int t = threadIdx.x;
    int s = lower_bound_dev(batch, NN, g);
    int e = lower_bound_dev(batch, NN, g + 1);
    float cnt = fmaxf((float)(e - s), 1.0f);
    p[t] = pooled[g * HH + t] / cnt;
    __syncthreads();
    if (t < 64) {
        float acc = hb1[t];
        for (int k = 0; k < HH; ++k) acc += p[k] * hw1[k * 64 + t];
        o1[t] = fmaxf(acc, 0.f);
    }
    __syncthreads();
    if (t < 32) {
        float acc = hb2[t];
        for (int k = 0; k < 64; ++k) acc += o1[k] * hw2[k * 32 + t];
        o2[t] = fmaxf(acc, 0.f);
    }
    __syncthreads();
    if (t == 0) {
        float acc = hb3[0];
        for (int k = 0; k < 32; ++k) acc += o2[k] * hw3[k];
        out[g] = acc;
    }
}

extern "C" void kernel_launch(void* const* d_in, const int* in_sizes, int n_in,
                              void* d_out, int out_size, void* d_ws, size_t ws_size,
                              hipStream_t stream)
{
    const float* x      = (const float*)d_in[0];
    const float* eattr  = (const float*)d_in[1];
    const float* node_w = (const float*)d_in[2];
    const float* node_b = (const float*)d_in[3];
    const float* edge_w = (const float*)d_in[4];
    const float* edge_b = (const float*)d_in[5];
    const float* tptr   = (const float*)d_in[6];
    const float* lin1_w = (const float*)d_in[7];
    const float* lin1_b = (const float*)d_in[8];
    const float* ln1_g  = (const float*)d_in[9];
    const float* ln1_bt = (const float*)d_in[10];
    const float* lin2_w = (const float*)d_in[11];
    const float* lin2_b = (const float*)d_in[12];
    const float* blk_g  = (const float*)d_in[13];
    const float* blk_b  = (const float*)d_in[14];
    const float* hw1    = (const float*)d_in[15];
    const float* hb1    = (const float*)d_in[16];
    const float* hw2    = (const float*)d_in[17];
    const float* hb2    = (const float*)d_in[18];
    const float* hw3    = (const float*)d_in[19];
    const float* hb3    = (const float*)d_in[20];
    const int*   eidx   = (const int*)d_in[21];
    const int*   batch  = (const int*)d_in[22];
    const int* src = eidx;
    const int* dst = eidx + NE;
    float* out = (float*)d_out;

    char* ws = (char*)d_ws;
    size_t off = 0;
    auto carve = [&](size_t bytes) -> char* {
        char* p = ws + off;
        off = (off + bytes + 255) & ~(size_t)255;
        return p;
    };
    float*    h      = (float*)carve((size_t)NN * HH * 4);
    _Float16* xh_in  = (_Float16*)carve((size_t)NX * 2);
    _Float16* xnh    = (_Float16*)carve((size_t)NN * HH * 2);
    _Float16* oh     = (_Float16*)carve((size_t)NN * HH * 2);
    _Float16* rh     = (_Float16*)carve((size_t)NN * HH * 2);
    _Float16* nwt    = (_Float16*)carve((size_t)16384 * 2);
    _Float16* w1t    = (_Float16*)carve((size_t)98304 * 2);
    _Float16* w2t    = (_Float16*)carve((size_t)98304 * 2);
    int*      counts = (int*)carve((size_t)NN * 4);
    int*      rank   = (int*)carve((size_t)NE * 4);
    int*      tmp    = (int*)carve((size_t)NN * 4);
    int*      btot   = (int*)carve((size_t)64 * 4);
    int*      boff   = (int*)carve((size_t)64 * 4);
    int*      rowp   = (int*)carve((size_t)(NN + 1) * 4);
    int2*     rec    = (int2*)carve((size_t)NE * 8);
    float*    pooled = (float*)carve((size_t)NG * HH * 4);

    hipMemsetAsync(counts, 0, (size_t)NN * 4, stream);
    hipMemsetAsync(pooled, 0, (size_t)NG * HH * 4, stream);

    {
        int total = NX4 + 16384 + 98304 + 98304;
        convert_kernel<<<(total + 255) / 256, 256, 0, stream>>>(
            x, node_w, lin1_w, lin2_w, xh_in, nwt, w1t, w2t);
    }
    const int NB = (NN + 1023) / 1024;   // 40
    count_rank_kernel<<<(NE + 255) / 256, 256, 0, stream>>>(dst, counts, rank);
    scanA_kernel<<<NB, 1024, 0, stream>>>(counts, tmp, btot);
    scanB_kernel<<<1, 64, 0, stream>>>(btot, boff, NB);
    scanC_kernel<<<NB, 1024, 0, stream>>>(tmp, boff, rowp);
    fill2_kernel<<<(NE + 255) / 256, 256, 0, stream>>>(src, dst, eattr, rowp, rank, rec);

    // node linear: xnh = half(x @ node_w + node_b)
    gemm_mfma<<<dim3(1, NN / 64), 256, 0, stream>>>(xh_in, nwt, node_b, xnh, NN, HH, DIM_IN);

    // layer 0 (no residual; post-LN uses blk[1])
    agg_kernel<<<NN / 4, 256, 0, stream>>>(xnh, rowp, rec, edge_w, edge_b, tptr, 0, oh);
    mlp_fused<0><<<NN / 64, 256, 0, stream>>>(
        oh, w1t, lin1_b, ln1_g, ln1_bt, w2t, lin2_b,
        h, blk_g + 1 * HH, blk_b + 1 * HH, xnh);
    // layer 1 (residual; post-LN uses blk[2])
    agg_kernel<<<NN / 4, 256, 0, stream>>>(xnh, rowp, rec, edge_w, edge_b, tptr, 1, oh);
    mlp_fused<1><<<NN / 64, 256, 0, stream>>>(
        oh, w1t + 32768, lin1_b + HH2, ln1_g + HH2, ln1_bt + HH2, w2t + 32768, lin2_b + HH,
        h, blk_g + 2 * HH, blk_b + 2 * HH, xnh);
    // layer 2 (residual; final LN uses blk[0] -> rh)
    agg_kernel<<<NN / 4, 256, 0, stream>>>(xnh, rowp, rec, edge_w, edge_b, tptr, 2, oh);
    mlp_fused<1><<<NN / 64, 256, 0, stream>>>(
        oh, w1t + 2 * 32768, lin1_b + 2 * HH2, ln1_g + 2 * HH2, ln1_bt + 2 * HH2,
        w2t + 2 * 32768, lin2_b + 2 * HH,
        h, blk_g, blk_b, rh);

    pool_kernel<<<dim3(NG, 8), 128, 0, stream>>>(rh, batch, pooled);
    head_kernel<<<NG, 128, 0, stream>>>(pooled, batch, hw1, hb1, hw2, hb2, hw3, hb3, out);
}